// Round 1
// baseline (424.883 us; speedup 1.0000x reference)
//
#include <hip/hip_runtime.h>
#include <math.h>

#define NN 4096
#define DD 512
#define MARGINF 1.0f

// ws layout (floats):
// [0, 4096)        sq[i] = ||x_i||^2
// [4096, 8192)     neg_sum[i]
// [8192]           sum of hinge^2 over triu positive pairs
// [8193]           count of triu positive pairs (stored as float)

__global__ void init_ws_kernel(float* __restrict__ ws) {
    int t = blockIdx.x * blockDim.x + threadIdx.x;
    if (t < NN) ws[NN + t] = 0.0f;
    if (t < 2)  ws[2 * NN + t] = 0.0f;
}

// One wave (64 lanes) per row; 4 rows per 256-thread block.
__global__ __launch_bounds__(256) void row_sq_kernel(const float* __restrict__ X,
                                                     float* __restrict__ ws) {
    int wave = threadIdx.x >> 6;
    int lane = threadIdx.x & 63;
    int row  = blockIdx.x * 4 + wave;
    const float4* xr = (const float4*)(X + (size_t)row * DD);
    float4 a = xr[lane];
    float4 b = xr[lane + 64];
    float s = a.x * a.x + a.y * a.y + a.z * a.z + a.w * a.w
            + b.x * b.x + b.y * b.y + b.z * b.z + b.w * b.w;
#pragma unroll
    for (int off = 32; off; off >>= 1) s += __shfl_down(s, off, 64);
    if (lane == 0) ws[row] = s;
}

// Tiled Gram (64x64 tile, BK=32, 4x4 micro-tile) fused with
// masked exp(1 - dist) row-sum into neg_sum via atomics.
#define BI 64
#define BJ 64
#define BK 32
#define LSTRIDE 68   // BI + 4 pad, keeps float4 alignment, breaks pow2 bank stride

__global__ __launch_bounds__(256) void negsum_kernel(const float* __restrict__ X,
                                                     const int* __restrict__ tgt,
                                                     float* __restrict__ ws) {
    __shared__ float As[BK][LSTRIDE];   // k-major: As[k][i]
    __shared__ float Bs[BK][LSTRIDE];   // k-major: Bs[k][j]
    __shared__ int   ti_l[BI];
    __shared__ int   tj_l[BJ];
    __shared__ float sqi_l[BI];
    __shared__ float sqj_l[BJ];

    const int i0 = blockIdx.y * BI;
    const int j0 = blockIdx.x * BJ;
    const int tid = threadIdx.x;
    const int tx = tid & 15;     // j micro index
    const int ty = tid >> 4;     // i micro index

    if (tid < BI) {
        ti_l[tid]  = tgt[i0 + tid];
        sqi_l[tid] = ws[i0 + tid];
    } else if (tid < 2 * BI) {
        int t = tid - BI;
        tj_l[t]  = tgt[j0 + t];
        sqj_l[t] = ws[j0 + t];
    }

    // staging indices: thread loads float4 (4c..4c+3) of rows r and r+32
    const int r  = tid >> 3;     // 0..31
    const int c  = tid & 7;      // 0..7 (float4 slot)

    float acc[4][4] = {};

    for (int k0 = 0; k0 < DD; k0 += BK) {
        float4 va0 = *(const float4*)(X + (size_t)(i0 + r)      * DD + k0 + 4 * c);
        float4 va1 = *(const float4*)(X + (size_t)(i0 + r + 32) * DD + k0 + 4 * c);
        float4 vb0 = *(const float4*)(X + (size_t)(j0 + r)      * DD + k0 + 4 * c);
        float4 vb1 = *(const float4*)(X + (size_t)(j0 + r + 32) * DD + k0 + 4 * c);
        __syncthreads();   // protect LDS from previous iteration's readers
        As[4 * c + 0][r] = va0.x;  As[4 * c + 1][r] = va0.y;
        As[4 * c + 2][r] = va0.z;  As[4 * c + 3][r] = va0.w;
        As[4 * c + 0][r + 32] = va1.x;  As[4 * c + 1][r + 32] = va1.y;
        As[4 * c + 2][r + 32] = va1.z;  As[4 * c + 3][r + 32] = va1.w;
        Bs[4 * c + 0][r] = vb0.x;  Bs[4 * c + 1][r] = vb0.y;
        Bs[4 * c + 2][r] = vb0.z;  Bs[4 * c + 3][r] = vb0.w;
        Bs[4 * c + 0][r + 32] = vb1.x;  Bs[4 * c + 1][r + 32] = vb1.y;
        Bs[4 * c + 2][r + 32] = vb1.z;  Bs[4 * c + 3][r + 32] = vb1.w;
        __syncthreads();

#pragma unroll
        for (int k = 0; k < BK; ++k) {
            float4 av = *(const float4*)&As[k][4 * ty];
            float4 bv = *(const float4*)&Bs[k][4 * tx];
            float a_[4] = {av.x, av.y, av.z, av.w};
            float b_[4] = {bv.x, bv.y, bv.z, bv.w};
#pragma unroll
            for (int u = 0; u < 4; ++u)
#pragma unroll
                for (int v = 0; v < 4; ++v)
                    acc[u][v] += a_[u] * b_[v];
        }
    }
    __syncthreads();

    // epilogue: masked exp(1 - dist), reduce over j
#pragma unroll
    for (int u = 0; u < 4; ++u) {
        int ii = 4 * ty + u;
        int lti = ti_l[ii];
        float si = sqi_l[ii];
        float part = 0.0f;
#pragma unroll
        for (int v = 0; v < 4; ++v) {
            int jj = 4 * tx + v;
            if (tj_l[jj] != lti) {
                float d2 = si + sqj_l[jj] - 2.0f * acc[u][v];
                float dist = d2 > 0.0f ? sqrtf(d2) : 0.0f;
                part += expf(MARGINF - dist);
            }
        }
        // reduce across tx (lane bits [3:0])
        part += __shfl_xor(part, 1, 64);
        part += __shfl_xor(part, 2, 64);
        part += __shfl_xor(part, 4, 64);
        part += __shfl_xor(part, 8, 64);
        if (tx == 0) atomicAdd(&ws[NN + i0 + ii], part);
    }
}

// Per row i: compact positive j (j>i, same label) into LDS, then each wave
// computes one pair's 512-elem dot cooperatively.
__global__ __launch_bounds__(256) void loss_kernel(const float* __restrict__ X,
                                                   const int* __restrict__ tgt,
                                                   const float* __restrict__ ws,
                                                   float* __restrict__ acc_out) {
    __shared__ float4 xi[DD / 4];
    __shared__ int plist[NN];
    __shared__ int pcnt;
    __shared__ float wsum[4];

    const int i = blockIdx.x;
    const int tid = threadIdx.x;
    if (tid == 0) pcnt = 0;
    const float4* xr = (const float4*)(X + (size_t)i * DD);
    if (tid < DD / 4) xi[tid] = xr[tid];
    const int ti = tgt[i];
    __syncthreads();

    for (int j = i + 1 + tid; j < NN; j += 256) {
        if (tgt[j] == ti) {
            int p = atomicAdd(&pcnt, 1);
            plist[p] = j;
        }
    }
    __syncthreads();

    const int cnt = pcnt;
    const float si  = ws[i];
    const float nsi = ws[NN + i];
    const int wave = tid >> 6;
    const int lane = tid & 63;
    float lsum = 0.0f;

    for (int p = wave; p < cnt; p += 4) {
        int j = plist[p];
        const float4* xj = (const float4*)(X + (size_t)j * DD);
        float4 a0 = xi[lane],      b0 = xj[lane];
        float4 a1 = xi[lane + 64], b1 = xj[lane + 64];
        float dot = a0.x * b0.x + a0.y * b0.y + a0.z * b0.z + a0.w * b0.w
                  + a1.x * b1.x + a1.y * b1.y + a1.z * b1.z + a1.w * b1.w;
#pragma unroll
        for (int off = 32; off; off >>= 1) dot += __shfl_xor(dot, off, 64);
        if (lane == 0) {
            float d2 = si + ws[j] - 2.0f * dot;
            float dist = d2 > 0.0f ? sqrtf(d2) : 0.0f;
            float J = logf(nsi + ws[NN + j]) + dist;
            float h = fmaxf(J, 0.0f);
            lsum += h * h;
        }
    }

    if (lane == 0) wsum[wave] = lsum;
    __syncthreads();
    if (tid == 0) {
        float s = wsum[0] + wsum[1] + wsum[2] + wsum[3];
        if (s != 0.0f) atomicAdd(&acc_out[0], s);
        if (cnt)       atomicAdd(&acc_out[1], (float)cnt);
    }
}

__global__ void finalize_kernel(const float* __restrict__ ws, float* __restrict__ out) {
    if (threadIdx.x == 0 && blockIdx.x == 0) {
        out[0] = ws[2 * NN] / (2.0f * ws[2 * NN + 1]);
    }
}

extern "C" void kernel_launch(void* const* d_in, const int* in_sizes, int n_in,
                              void* d_out, int out_size, void* d_ws, size_t ws_size,
                              hipStream_t stream) {
    const float* X  = (const float*)d_in[0];
    const int*  tgt = (const int*)d_in[1];
    float* ws  = (float*)d_ws;
    float* out = (float*)d_out;

    hipLaunchKernelGGL(init_ws_kernel, dim3(16), dim3(256), 0, stream, ws);
    hipLaunchKernelGGL(row_sq_kernel, dim3(NN / 4), dim3(256), 0, stream, X, ws);
    hipLaunchKernelGGL(negsum_kernel, dim3(NN / BJ, NN / BI), dim3(256), 0, stream,
                       X, tgt, ws);
    hipLaunchKernelGGL(loss_kernel, dim3(NN), dim3(256), 0, stream,
                       X, tgt, ws, ws + 2 * NN);
    hipLaunchKernelGGL(finalize_kernel, dim3(1), dim3(64), 0, stream, ws, out);
}

// Round 2
// 206.325 us; speedup vs baseline: 2.0593x; 2.0593x over previous
//
#include <hip/hip_runtime.h>
#include <math.h>

#define NN 4096
#define DD 512
#define MARGINF 1.0f
#define NCLS 64
#define MAXM 160

typedef __attribute__((ext_vector_type(8))) short bf16x8;  // 8 bf16 (4 VGPRs)
typedef __attribute__((ext_vector_type(4))) float f32x4;   // 4 fp32 acc

// ws layout (float indices):
#define WS_SQ   0        // [4096] ||x_i||^2
#define WS_NS   4096     // [4096] neg_sum
#define WS_LOSS 8192     // [1] sum hinge^2 over unordered positive pairs
#define WS_CNT  8256     // int[64] class counts
#define WS_MEM  8320     // int[64*160] class member lists
#define WS_XB   32768    // ushort[4096*512] bf16 copy of X (4 MB)

__device__ __forceinline__ unsigned short f2bf(float f) {
    unsigned u = __float_as_uint(f);
    u += 0x7fffu + ((u >> 16) & 1u);   // round-to-nearest-even
    return (unsigned short)(u >> 16);
}

__device__ __forceinline__ void gl_lds16(const void* g, void* l) {
    __builtin_amdgcn_global_load_lds(
        (__attribute__((address_space(1))) unsigned int*)g,
        (__attribute__((address_space(3))) unsigned int*)l,
        16, 0, 0);
}

// Fused: row norms (fp32) + bf16 conversion + ws zeroing. One wave per row.
__global__ __launch_bounds__(256) void prep_kernel(const float* __restrict__ X,
                                                   float* __restrict__ ws) {
    const int wv = threadIdx.x >> 6, lane = threadIdx.x & 63;
    const int row = blockIdx.x * 4 + wv;
    const float4* xr = (const float4*)(X + (size_t)row * DD);
    float4 a = xr[lane], b = xr[lane + 64];
    float s = a.x * a.x + a.y * a.y + a.z * a.z + a.w * a.w
            + b.x * b.x + b.y * b.y + b.z * b.z + b.w * b.w;
#pragma unroll
    for (int off = 32; off; off >>= 1) s += __shfl_down(s, off, 64);
    if (lane == 0) { ws[WS_SQ + row] = s; ws[WS_NS + row] = 0.0f; }
    ushort4 pa = {f2bf(a.x), f2bf(a.y), f2bf(a.z), f2bf(a.w)};
    ushort4 pb = {f2bf(b.x), f2bf(b.y), f2bf(b.z), f2bf(b.w)};
    ushort4* xb = (ushort4*)((unsigned short*)(ws + WS_XB) + (size_t)row * DD);
    xb[lane] = pa;
    xb[lane + 64] = pb;
    if (blockIdx.x == 0) {
        if (threadIdx.x < NCLS) ((int*)(ws + WS_CNT))[threadIdx.x] = 0;
        if (threadIdx.x == 0) ws[WS_LOSS] = 0.0f;
    }
}

__global__ __launch_bounds__(256) void class_build_kernel(const int* __restrict__ tgt,
                                                          float* __restrict__ ws) {
    const int t = blockIdx.x * 256 + threadIdx.x;
    const int c = tgt[t];
    int* counts = (int*)(ws + WS_CNT);
    int* mem = (int*)(ws + WS_MEM);
    int p = atomicAdd(&counts[c], 1);
    if (p < MAXM) mem[c * MAXM + p] = t;
}

// Gram via bf16 MFMA (128x128 tile, BK=32), triangular grid (bi<=bj),
// fused masked exp(1-dist) row+col sums into neg_sum.
__global__ __launch_bounds__(256) void negsum_kernel(const int* __restrict__ tgt,
                                                     float* __restrict__ ws) {
    __shared__ unsigned short As[128 * 32];
    __shared__ unsigned short Bs[128 * 32];

    const int bidx = blockIdx.x;
    int bj = (int)((sqrtf(8.0f * (float)bidx + 1.0f) - 1.0f) * 0.5f);
    while (bj * (bj + 1) / 2 > bidx) --bj;
    while ((bj + 1) * (bj + 2) / 2 <= bidx) ++bj;
    const int bi = bidx - bj * (bj + 1) / 2;   // bi <= bj
    const int i0 = bi * 128, j0 = bj * 128;

    const int tid = threadIdx.x;
    const int w = tid >> 6, lane = tid & 63;
    const int lr = lane >> 2, lc = lane & 3;
    const unsigned short* Xb = (const unsigned short*)(ws + WS_XB);

    const unsigned short* ga0 = Xb + (size_t)(i0 + w * 16 + lr) * DD + lc * 8;
    const unsigned short* ga1 = ga0 + (size_t)64 * DD;
    const unsigned short* gb0 = Xb + (size_t)(j0 + w * 16 + lr) * DD + lc * 8;
    const unsigned short* gb1 = gb0 + (size_t)64 * DD;
    unsigned short* la0 = &As[(w * 16) * 32];       // wave-uniform LDS bases
    unsigned short* la1 = &As[(64 + w * 16) * 32];
    unsigned short* lb0 = &Bs[(w * 16) * 32];
    unsigned short* lb1 = &Bs[(64 + w * 16) * 32];

    const int m_ = lane & 15, q = lane >> 4;
    const int wrow = (w >> 1) * 64, wcol = (w & 1) * 64;

    f32x4 acc[4][4] = {};

    for (int k0 = 0; k0 < DD; k0 += 32) {
        __syncthreads();                       // prev readers done
        gl_lds16(ga0 + k0, la0);
        gl_lds16(ga1 + k0, la1);
        gl_lds16(gb0 + k0, lb0);
        gl_lds16(gb1 + k0, lb1);
        __syncthreads();                       // vmcnt(0) drains before barrier
        bf16x8 af[4], bf[4];
#pragma unroll
        for (int u = 0; u < 4; ++u)
            af[u] = *(const bf16x8*)&As[(wrow + u * 16 + m_) * 32 + q * 8];
#pragma unroll
        for (int v = 0; v < 4; ++v)
            bf[v] = *(const bf16x8*)&Bs[(wcol + v * 16 + m_) * 32 + q * 8];
#pragma unroll
        for (int u = 0; u < 4; ++u)
#pragma unroll
            for (int v = 0; v < 4; ++v)
                acc[u][v] = __builtin_amdgcn_mfma_f32_16x16x32_bf16(
                    af[u], bf[v], acc[u][v], 0, 0, 0);
    }

    // epilogue: C/D map col=lane&15, row=(lane>>4)*4+reg
    const float* sq = ws + WS_SQ;
    float* ns = ws + WS_NS;
    float sjv[4]; int tjv[4];
#pragma unroll
    for (int v = 0; v < 4; ++v) {
        int j = j0 + wcol + v * 16 + m_;
        sjv[v] = sq[j];
        tjv[v] = tgt[j];
    }
    float colp[4] = {0.0f, 0.0f, 0.0f, 0.0f};
#pragma unroll
    for (int u = 0; u < 4; ++u) {
#pragma unroll
        for (int r = 0; r < 4; ++r) {
            const int i = i0 + wrow + u * 16 + q * 4 + r;
            const float si = sq[i];
            const int ti = tgt[i];
            float rp = 0.0f;
#pragma unroll
            for (int v = 0; v < 4; ++v) {
                float d2 = si + sjv[v] - 2.0f * acc[u][v][r];
                float dist = d2 > 0.0f ? sqrtf(d2) : 0.0f;
                float e = (tjv[v] != ti) ? __expf(MARGINF - dist) : 0.0f;
                rp += e;
                colp[v] += e;
            }
            rp += __shfl_xor(rp, 1, 64);
            rp += __shfl_xor(rp, 2, 64);
            rp += __shfl_xor(rp, 4, 64);
            rp += __shfl_xor(rp, 8, 64);
            if (m_ == 0) atomicAdd(&ns[i], rp);
        }
    }
    if (bi != bj) {   // symmetric contribution: G[j][i] == G[i][j]
#pragma unroll
        for (int v = 0; v < 4; ++v) {
            float cp = colp[v];
            cp += __shfl_xor(cp, 16, 64);
            cp += __shfl_xor(cp, 32, 64);
            if (q == 0) atomicAdd(&ns[j0 + wcol + v * 16 + m_], cp);
        }
    }
}

// Positive pairs: enumerate intra-class unordered pairs, wave-cooperative dot.
__global__ __launch_bounds__(256) void pair_kernel(const float* __restrict__ X,
                                                   float* __restrict__ ws) {
    const int c = blockIdx.y, chunk = blockIdx.x;   // 16 chunks
    const int wv = threadIdx.x >> 6, lane = threadIdx.x & 63;
    int mc = ((const int*)(ws + WS_CNT))[c];
    if (mc > MAXM) mc = MAXM;
    const int P = mc * (mc - 1) / 2;
    const int* mem = (const int*)(ws + WS_MEM) + c * MAXM;
    const float* sq = ws + WS_SQ;
    const float* ns = ws + WS_NS;
    float lsum = 0.0f;
    for (int p = chunk * 4 + wv; p < P; p += 64) {
        int b = (int)((1.0f + sqrtf(1.0f + 8.0f * (float)p)) * 0.5f);
        while (b * (b - 1) / 2 > p) --b;
        while ((b + 1) * b / 2 <= p) ++b;
        const int a = p - b * (b - 1) / 2;
        const int i = mem[a], j = mem[b];
        const float4* xi = (const float4*)(X + (size_t)i * DD);
        const float4* xj = (const float4*)(X + (size_t)j * DD);
        float4 A0 = xi[lane], B0 = xj[lane];
        float4 A1 = xi[lane + 64], B1 = xj[lane + 64];
        float dot = A0.x * B0.x + A0.y * B0.y + A0.z * B0.z + A0.w * B0.w
                  + A1.x * B1.x + A1.y * B1.y + A1.z * B1.z + A1.w * B1.w;
#pragma unroll
        for (int off = 32; off; off >>= 1) dot += __shfl_xor(dot, off, 64);
        if (lane == 0) {
            float d2 = sq[i] + sq[j] - 2.0f * dot;
            float dist = d2 > 0.0f ? sqrtf(d2) : 0.0f;
            float J = __logf(ns[i] + ns[j]) + dist;
            float h = fmaxf(J, 0.0f);
            lsum += h * h;
        }
    }
    if (lane == 0 && lsum != 0.0f) atomicAdd(&ws[WS_LOSS], lsum);
}

__global__ void finalize_kernel(const float* __restrict__ ws, float* __restrict__ out) {
    const int t = threadIdx.x;
    int mcv = (t < NCLS) ? ((const int*)(ws + WS_CNT))[t] : 0;
    float lp = (float)(mcv * (mcv - 1));   // len_p = sum over classes m*(m-1)
#pragma unroll
    for (int off = 32; off; off >>= 1) lp += __shfl_down(lp, off, 64);
    if (t == 0) out[0] = ws[WS_LOSS] / lp;
}

extern "C" void kernel_launch(void* const* d_in, const int* in_sizes, int n_in,
                              void* d_out, int out_size, void* d_ws, size_t ws_size,
                              hipStream_t stream) {
    const float* X  = (const float*)d_in[0];
    const int*  tgt = (const int*)d_in[1];
    float* ws  = (float*)d_ws;
    float* out = (float*)d_out;

    hipLaunchKernelGGL(prep_kernel, dim3(NN / 4), dim3(256), 0, stream, X, ws);
    hipLaunchKernelGGL(class_build_kernel, dim3(NN / 256), dim3(256), 0, stream, tgt, ws);
    hipLaunchKernelGGL(negsum_kernel, dim3(528), dim3(256), 0, stream, tgt, ws);
    hipLaunchKernelGGL(pair_kernel, dim3(16, NCLS), dim3(256), 0, stream, X, ws);
    hipLaunchKernelGGL(finalize_kernel, dim3(1), dim3(64), 0, stream, ws, out);
}

// Round 3
// 121.732 us; speedup vs baseline: 3.4903x; 1.6949x over previous
//
#include <hip/hip_runtime.h>
#include <math.h>

#define NN 4096
#define DD 512
#define MARGINF 1.0f
#define NCLS 64
#define MAXM 160
#define TRI (MAXM * (MAXM - 1) / 2)   // 12720

typedef __attribute__((ext_vector_type(8))) short bf16x8;  // 8 bf16 (4 VGPRs)
typedef __attribute__((ext_vector_type(4))) float f32x4;   // 4 fp32 acc

// ws layout (float indices):
#define WS_SQ   0         // float[4096] ||x_i||^2
#define WS_NS   4096      // float[4096] neg_sum
#define WS_LOSS 8192      // float[1] sum hinge^2 over unordered positive pairs
#define WS_CNT  8256      // int[64] class counts
#define WS_RK   8320      // int[4096] rank of i within its class
#define WS_MEM  12416     // int[64*160] class member lists
#define WS_XB   32768     // ushort[4096*512] bf16 copy of X (4 MB)
#define WS_PD   1081344   // float[64*TRI] positive-pair distances (3.3 MB)

__device__ __forceinline__ unsigned short f2bf(float f) {
    unsigned u = __float_as_uint(f);
    u += 0x7fffu + ((u >> 16) & 1u);   // round-to-nearest-even
    return (unsigned short)(u >> 16);
}

__device__ __forceinline__ void gl_lds16(const void* g, void* l) {
    __builtin_amdgcn_global_load_lds(
        (__attribute__((address_space(1))) unsigned int*)g,
        (__attribute__((address_space(3))) unsigned int*)l,
        16, 0, 0);
}

// Fused: row norms (fp32) + bf16 conversion + ws zeroing. One wave per row.
__global__ __launch_bounds__(256) void prep_kernel(const float* __restrict__ X,
                                                   float* __restrict__ ws) {
    const int wv = threadIdx.x >> 6, lane = threadIdx.x & 63;
    const int row = blockIdx.x * 4 + wv;
    const float4* xr = (const float4*)(X + (size_t)row * DD);
    float4 a = xr[lane], b = xr[lane + 64];
    float s = a.x * a.x + a.y * a.y + a.z * a.z + a.w * a.w
            + b.x * b.x + b.y * b.y + b.z * b.z + b.w * b.w;
#pragma unroll
    for (int off = 32; off; off >>= 1) s += __shfl_down(s, off, 64);
    if (lane == 0) { ws[WS_SQ + row] = s; ws[WS_NS + row] = 0.0f; }
    ushort4 pa = {f2bf(a.x), f2bf(a.y), f2bf(a.z), f2bf(a.w)};
    ushort4 pb = {f2bf(b.x), f2bf(b.y), f2bf(b.z), f2bf(b.w)};
    ushort4* xb = (ushort4*)((unsigned short*)(ws + WS_XB) + (size_t)row * DD);
    xb[lane] = pa;
    xb[lane + 64] = pb;
    if (blockIdx.x == 0) {
        if (threadIdx.x < NCLS) ((int*)(ws + WS_CNT))[threadIdx.x] = 0;
        if (threadIdx.x == 0) ws[WS_LOSS] = 0.0f;
    }
}

__global__ __launch_bounds__(256) void class_build_kernel(const int* __restrict__ tgt,
                                                          float* __restrict__ ws) {
    const int t = blockIdx.x * 256 + threadIdx.x;
    const int c = tgt[t];
    int* counts = (int*)(ws + WS_CNT);
    int* rk  = (int*)(ws + WS_RK);
    int* mem = (int*)(ws + WS_MEM);
    int p = atomicAdd(&counts[c], 1);
    rk[t] = p;
    if (p < MAXM) mem[c * MAXM + p] = t;
}

// Gram via bf16 MFMA (128x128 tile, BK=32), triangular grid (bi<=bj),
// fused masked exp(1-dist) row+col sums into neg_sum; positive-pair dist
// captured into posd (each unordered pair visited exactly once with i<j).
__global__ __launch_bounds__(256) void negsum_kernel(const int* __restrict__ tgt,
                                                     float* __restrict__ ws) {
    __shared__ unsigned short As[128 * 32];
    __shared__ unsigned short Bs[128 * 32];

    const int bidx = blockIdx.x;
    int bj = (int)((sqrtf(8.0f * (float)bidx + 1.0f) - 1.0f) * 0.5f);
    while (bj * (bj + 1) / 2 > bidx) --bj;
    while ((bj + 1) * (bj + 2) / 2 <= bidx) ++bj;
    const int bi = bidx - bj * (bj + 1) / 2;   // bi <= bj
    const int i0 = bi * 128, j0 = bj * 128;

    const int tid = threadIdx.x;
    const int w = tid >> 6, lane = tid & 63;
    const int lr = lane >> 2, lc = lane & 3;
    const unsigned short* Xb = (const unsigned short*)(ws + WS_XB);

    const unsigned short* ga0 = Xb + (size_t)(i0 + w * 16 + lr) * DD + lc * 8;
    const unsigned short* ga1 = ga0 + (size_t)64 * DD;
    const unsigned short* gb0 = Xb + (size_t)(j0 + w * 16 + lr) * DD + lc * 8;
    const unsigned short* gb1 = gb0 + (size_t)64 * DD;
    unsigned short* la0 = &As[(w * 16) * 32];       // wave-uniform LDS bases
    unsigned short* la1 = &As[(64 + w * 16) * 32];
    unsigned short* lb0 = &Bs[(w * 16) * 32];
    unsigned short* lb1 = &Bs[(64 + w * 16) * 32];

    const int m_ = lane & 15, q = lane >> 4;
    const int wrow = (w >> 1) * 64, wcol = (w & 1) * 64;

    f32x4 acc[4][4] = {};

    for (int k0 = 0; k0 < DD; k0 += 32) {
        __syncthreads();                       // prev readers done
        gl_lds16(ga0 + k0, la0);
        gl_lds16(ga1 + k0, la1);
        gl_lds16(gb0 + k0, lb0);
        gl_lds16(gb1 + k0, lb1);
        __syncthreads();                       // vmcnt(0) drains before barrier
        bf16x8 af[4], bf[4];
#pragma unroll
        for (int u = 0; u < 4; ++u)
            af[u] = *(const bf16x8*)&As[(wrow + u * 16 + m_) * 32 + q * 8];
#pragma unroll
        for (int v = 0; v < 4; ++v)
            bf[v] = *(const bf16x8*)&Bs[(wcol + v * 16 + m_) * 32 + q * 8];
#pragma unroll
        for (int u = 0; u < 4; ++u)
#pragma unroll
            for (int v = 0; v < 4; ++v)
                acc[u][v] = __builtin_amdgcn_mfma_f32_16x16x32_bf16(
                    af[u], bf[v], acc[u][v], 0, 0, 0);
    }

    // epilogue: C/D map col=lane&15, row=(lane>>4)*4+reg
    const float* sq = ws + WS_SQ;
    float* ns = ws + WS_NS;
    const int* rk = (const int*)(ws + WS_RK);
    float* posd = ws + WS_PD;
    float sjv[4]; int tjv[4], jv[4];
#pragma unroll
    for (int v = 0; v < 4; ++v) {
        int j = j0 + wcol + v * 16 + m_;
        jv[v] = j;
        sjv[v] = sq[j];
        tjv[v] = tgt[j];
    }
    float colp[4] = {0.0f, 0.0f, 0.0f, 0.0f};
#pragma unroll
    for (int u = 0; u < 4; ++u) {
#pragma unroll
        for (int r = 0; r < 4; ++r) {
            const int i = i0 + wrow + u * 16 + q * 4 + r;
            const float si = sq[i];
            const int ti = tgt[i];
            float rp = 0.0f;
#pragma unroll
            for (int v = 0; v < 4; ++v) {
                float d2 = si + sjv[v] - 2.0f * acc[u][v][r];
                float dist = d2 > 0.0f ? sqrtf(d2) : 0.0f;
                if (tjv[v] != ti) {
                    float e = __expf(MARGINF - dist);
                    rp += e;
                    colp[v] += e;
                } else if (i < jv[v]) {
                    int ra = rk[i], rb = rk[jv[v]];
                    if (ra < MAXM && rb < MAXM) {
                        int hi = ra > rb ? ra : rb;
                        int lo = ra > rb ? rb : ra;
                        posd[ti * TRI + hi * (hi - 1) / 2 + lo] = dist;
                    }
                }
            }
            rp += __shfl_xor(rp, 1, 64);
            rp += __shfl_xor(rp, 2, 64);
            rp += __shfl_xor(rp, 4, 64);
            rp += __shfl_xor(rp, 8, 64);
            if (m_ == 0) atomicAdd(&ns[i], rp);
        }
    }
    if (bi != bj) {   // symmetric contribution: G[j][i] == G[i][j]
#pragma unroll
        for (int v = 0; v < 4; ++v) {
            float cp = colp[v];
            cp += __shfl_xor(cp, 16, 64);
            cp += __shfl_xor(cp, 32, 64);
            if (q == 0) atomicAdd(&ns[jv[v]], cp);
        }
    }
}

// Positive pairs: iterate stored distances per class, gather neg_sums, hinge^2.
__global__ __launch_bounds__(256) void pair2_kernel(float* __restrict__ ws) {
    __shared__ float wsum[4];
    const int c = blockIdx.x;
    int mc = ((const int*)(ws + WS_CNT))[c];
    if (mc > MAXM) mc = MAXM;
    const int P = mc * (mc - 1) / 2;
    const int* mem = (const int*)(ws + WS_MEM) + c * MAXM;
    const float* pd = ws + WS_PD + c * TRI;
    const float* ns = ws + WS_NS;
    float lsum = 0.0f;
    for (int p = threadIdx.x; p < P; p += 256) {
        int b = (int)((1.0f + sqrtf(1.0f + 8.0f * (float)p)) * 0.5f);
        while (b * (b - 1) / 2 > p) --b;
        while ((b + 1) * b / 2 <= p) ++b;
        const int a = p - b * (b - 1) / 2;
        const float dist = pd[b * (b - 1) / 2 + a];
        const int i = mem[a], j = mem[b];
        float J = __logf(ns[i] + ns[j]) + dist;
        float h = fmaxf(J, 0.0f);
        lsum += h * h;
    }
#pragma unroll
    for (int off = 32; off; off >>= 1) lsum += __shfl_xor(lsum, off, 64);
    const int wv = threadIdx.x >> 6, lane = threadIdx.x & 63;
    if (lane == 0) wsum[wv] = lsum;
    __syncthreads();
    if (threadIdx.x == 0) {
        float s = wsum[0] + wsum[1] + wsum[2] + wsum[3];
        if (s != 0.0f) atomicAdd(&ws[WS_LOSS], s);
    }
}

__global__ void finalize_kernel(const float* __restrict__ ws, float* __restrict__ out) {
    const int t = threadIdx.x;
    int mcv = (t < NCLS) ? ((const int*)(ws + WS_CNT))[t] : 0;
    float lp = (float)(mcv * (mcv - 1));   // len_p = sum over classes m*(m-1)
#pragma unroll
    for (int off = 32; off; off >>= 1) lp += __shfl_down(lp, off, 64);
    if (t == 0) out[0] = ws[WS_LOSS] / lp;
}

extern "C" void kernel_launch(void* const* d_in, const int* in_sizes, int n_in,
                              void* d_out, int out_size, void* d_ws, size_t ws_size,
                              hipStream_t stream) {
    const float* X  = (const float*)d_in[0];
    const int*  tgt = (const int*)d_in[1];
    float* ws  = (float*)d_ws;
    float* out = (float*)d_out;

    hipLaunchKernelGGL(prep_kernel, dim3(NN / 4), dim3(256), 0, stream, X, ws);
    hipLaunchKernelGGL(class_build_kernel, dim3(NN / 256), dim3(256), 0, stream, tgt, ws);
    hipLaunchKernelGGL(negsum_kernel, dim3(528), dim3(256), 0, stream, tgt, ws);
    hipLaunchKernelGGL(pair2_kernel, dim3(NCLS), dim3(256), 0, stream, ws);
    hipLaunchKernelGGL(finalize_kernel, dim3(1), dim3(64), 0, stream, ws, out);
}